// Round 6
// baseline (1480.675 us; speedup 1.0000x reference)
//
#include <hip/hip_runtime.h>
#include <math.h>

#define N_NODE    1000000
#define N_BOND    100000
#define K_TWIST   40
#define MAX_ORDER 8
#define N_DOMAIN  10000
#define N_PER_DOM 100           // N_NODE / N_DOMAIN
#define N_GROUP   12500         // N_BOND / MAX_ORDER
#define N_TWIST   500000        // N_GROUP * K_TWIST  (nodes >= N_TWIST never twisted)
#define SIGMA_MAXF 3.14159265358979323846f

// Scratch discipline (proven R3/R4/R5):
//   ws: rt table only, 10000*12 floats = 480,000 B.
//   out-high floats [1.5M, 3.0M):
//     M0 = [1,500,000 , 1,650,000)   150k floats (ping)
//     M1 = [1,650,000 , 1,800,000)   150k floats (pong; final Mf)
//     bp = [1,800,000 , 3,000,000)   100k bonds x 12 floats (gather table)
//   All consumed before apply_high_k overwrites [1.5M, 3M).
// Cost model (R1/R3/R4/R5 fit): ~78 us fixed harness overhead per replay
// + ~2 us per dispatch + kernel work  =>  minimize dispatches AND work.

#define M0_OFF  1500000
#define M1_OFF  1650000
#define BP_OFF  1800000

// ---------------------------------------------------------------------------
// gather_k: one thread per bond. Coalesced pre-build of the bond record:
//   bp[12b +0..2] = pos[u], +3..5 = pos[v], +6 = cos(ang), +7 = sin(ang),
//   +8 = group(u) or -1 (u not twisted), +9 = group(v) or -1,
//   +10 = valid (anno order == b%8), +11 = pad.
// Angle depends only on bond inputs -> trig done ONCE here, not per order.
// ---------------------------------------------------------------------------
__global__ __launch_bounds__(256) void gather_k(
    const float* __restrict__ pos, const float* __restrict__ info_level,
    const int* __restrict__ anno, const float* __restrict__ eps,
    const float* __restrict__ uni, const int* __restrict__ from_prior_p,
    float* __restrict__ out)
{
    int b = blockIdx.x * 256 + threadIdx.x;
    if (b >= N_BOND) return;
    int o = b & (MAX_ORDER - 1);
    int u = anno[3*b + 1];
    int v = anno[3*b + 2];
    float info = info_level[b];
    float ang  = eps[b] * (1.0f - info) * SIGMA_MAXF;
    if (from_prior_p[0] != 0 && info == 0.0f) ang = uni[b];
    float4 r0, r1, r2;
    r0.x = pos[3*u+0]; r0.y = pos[3*u+1]; r0.z = pos[3*u+2];
    r0.w = pos[3*v+0]; r1.x = pos[3*v+1]; r1.y = pos[3*v+2];
    r1.z = cosf(ang);  r1.w = sinf(ang);
    r2.x = (u < N_TWIST) ? (float)(u / K_TWIST) : -1.0f;
    r2.y = (v < N_TWIST) ? (float)(v / K_TWIST) : -1.0f;
    r2.z = (anno[3*b] == o) ? 1.0f : 0.0f;
    r2.w = 0.0f;
    float4* bp4 = (float4*)(out + BP_OFF);
    bp4[3*b + 0] = r0;
    bp4[3*b + 1] = r1;
    bp4[3*b + 2] = r2;
}

// ---------------------------------------------------------------------------
// compose_all_k: SINGLE workgroup (1024 threads) runs all 8 order-levels,
// separated by __syncthreads() (workgroup barrier == cheap global barrier,
// replacing 7 stream-ordered dispatch boundaries). Per level, thread t
// handles groups g = t, t+1024, ... (13 iters). M tables are 600 KB,
// L1/L2-hot on the single CU. Endpoint current positions reconstructed as
// M_prev[group] * pos_orig (affine-composition math verified R4/R5).
// ---------------------------------------------------------------------------
__global__ __launch_bounds__(1024) void compose_all_k(float* __restrict__ out)
{
    const float4* bp4 = (const float4*)(out + BP_OFF);
    for (int o = 0; o < MAX_ORDER; o++) {
        const float* Mp = out + ((o & 1) ? M0_OFF : M1_OFF);  // prev (o>0 only)
        float*       Mc = out + ((o & 1) ? M1_OFF : M0_OFF);  // cur (o=7 -> M1)
        for (int g = threadIdx.x; g < N_GROUP; g += 1024) {
            int b = g * MAX_ORDER + o;
            float4 r0 = bp4[3*b + 0];
            float4 r1 = bp4[3*b + 1];
            float4 r2 = bp4[3*b + 2];
            float* mg = Mc + 12 * g;
            if (r2.z == 0.0f) {                  // invalid: no rotation this level
                if (o == 0) {
                    mg[0]=1.f; mg[1]=0.f; mg[2]=0.f;
                    mg[3]=0.f; mg[4]=1.f; mg[5]=0.f;
                    mg[6]=0.f; mg[7]=0.f; mg[8]=1.f;
                    mg[9]=0.f; mg[10]=0.f; mg[11]=0.f;
                } else {
                    const float* mp = Mp + 12 * g;
                    #pragma unroll
                    for (int k = 0; k < 12; k++) mg[k] = mp[k];
                }
                continue;
            }
            float pu0 = r0.x, pu1 = r0.y, pu2 = r0.z;
            float pv0 = r0.w, pv1 = r1.x, pv2 = r1.y;
            float c = r1.z, s = r1.w;
            if (o > 0) {
                int gu = (int)r2.x;
                int gv = (int)r2.y;
                if (gu >= 0) {
                    const float* m = Mp + 12 * gu;
                    float a0 = m[0]*pu0 + m[1]*pu1 + m[2]*pu2 + m[9];
                    float a1 = m[3]*pu0 + m[4]*pu1 + m[5]*pu2 + m[10];
                    float a2 = m[6]*pu0 + m[7]*pu1 + m[8]*pu2 + m[11];
                    pu0 = a0; pu1 = a1; pu2 = a2;
                }
                if (gv >= 0) {
                    const float* m = Mp + 12 * gv;
                    float a0 = m[0]*pv0 + m[1]*pv1 + m[2]*pv2 + m[9];
                    float a1 = m[3]*pv0 + m[4]*pv1 + m[5]*pv2 + m[10];
                    float a2 = m[6]*pv0 + m[7]*pv1 + m[8]*pv2 + m[11];
                    pv0 = a0; pv1 = a1; pv2 = a2;
                }
            }
            float ax = pv0-pu0, ay = pv1-pu1, az = pv2-pu2;
            float inv = 1.0f / (sqrtf(ax*ax + ay*ay + az*az) + 1e-12f);
            ax *= inv; ay *= inv; az *= inv;
            float t = 1.0f - c;
            float R00 = c + t*ax*ax,     R01 = -s*az + t*ax*ay, R02 =  s*ay + t*ax*az;
            float R10 =  s*az + t*ay*ax, R11 = c + t*ay*ay,     R12 = -s*ax + t*ay*az;
            float R20 = -s*ay + t*az*ax, R21 =  s*ax + t*az*ay, R22 = c + t*az*az;
            if (o == 0) {
                mg[0]=R00; mg[1]=R01; mg[2]=R02;
                mg[3]=R10; mg[4]=R11; mg[5]=R12;
                mg[6]=R20; mg[7]=R21; mg[8]=R22;
                mg[9]  = pv0 - (R00*pv0 + R01*pv1 + R02*pv2);
                mg[10] = pv1 - (R10*pv0 + R11*pv1 + R12*pv2);
                mg[11] = pv2 - (R20*pv0 + R21*pv1 + R22*pv2);
            } else {
                const float* mp = Mp + 12 * g;
                mg[0] = R00*mp[0] + R01*mp[3] + R02*mp[6];
                mg[1] = R00*mp[1] + R01*mp[4] + R02*mp[7];
                mg[2] = R00*mp[2] + R01*mp[5] + R02*mp[8];
                mg[3] = R10*mp[0] + R11*mp[3] + R12*mp[6];
                mg[4] = R10*mp[1] + R11*mp[4] + R12*mp[7];
                mg[5] = R10*mp[2] + R11*mp[5] + R12*mp[8];
                mg[6] = R20*mp[0] + R21*mp[3] + R22*mp[6];
                mg[7] = R20*mp[1] + R21*mp[4] + R22*mp[7];
                mg[8] = R20*mp[2] + R21*mp[5] + R22*mp[8];
                float d0 = mp[9]-pv0, d1 = mp[10]-pv1, d2 = mp[11]-pv2;
                mg[9]  = R00*d0 + R01*d1 + R02*d2 + pv0;
                mg[10] = R10*d0 + R11*d1 + R12*d2 + pv1;
                mg[11] = R20*d0 + R21*d1 + R22*d2 + pv2;
            }
        }
        __syncthreads();   // compiler drains vmcnt before s_barrier -> writes visible
    }
}

// ---------------------------------------------------------------------------
// Kabsch 3x3 SVD from 15 sums (double Jacobi on H^T H) — numerics identical
// to the R1/R3/R4/R5-verified version.
// ---------------------------------------------------------------------------
__device__ inline void cross3d(const double a[3], const double b[3], double r[3])
{
    r[0] = a[1]*b[2] - a[2]*b[1];
    r[1] = a[2]*b[0] - a[0]*b[2];
    r[2] = a[0]*b[1] - a[1]*b[0];
}

__device__ void kabsch_from_sums(const float* s, float* __restrict__ rt)
{
    const double inv_n = 1.0 / (double)N_PER_DOM;
    double sP[3] = { s[0], s[1], s[2] };
    double sQ[3] = { s[3], s[4], s[5] };
    double H[3][3];
    #pragma unroll
    for (int i = 0; i < 3; i++)
        #pragma unroll
        for (int j = 0; j < 3; j++)
            H[i][j] = (double)s[6 + 3*i + j] - sP[i]*sQ[j]*inv_n;
    double A[3][3];
    #pragma unroll
    for (int i = 0; i < 3; i++)
        #pragma unroll
        for (int j = 0; j < 3; j++)
            A[i][j] = H[0][i]*H[0][j] + H[1][i]*H[1][j] + H[2][i]*H[2][j];
    double V[3][3] = {{1,0,0},{0,1,0},{0,0,1}};
    for (int sweep = 0; sweep < 30; sweep++) {
        double off = A[0][1]*A[0][1] + A[0][2]*A[0][2] + A[1][2]*A[1][2];
        double n2  = A[0][0]*A[0][0] + A[1][1]*A[1][1] + A[2][2]*A[2][2];
        if (off <= 1e-28 * n2) break;
        for (int pp = 0; pp < 3; pp++) {
            int p = (pp == 2) ? 1 : 0;
            int q = (pp == 0) ? 1 : 2;
            double apq = A[p][q];
            if (apq == 0.0) continue;
            double tau = (A[q][q] - A[p][p]) / (2.0 * apq);
            double tj  = (tau >= 0.0 ? 1.0 : -1.0) / (fabs(tau) + sqrt(1.0 + tau*tau));
            double cj  = 1.0 / sqrt(1.0 + tj*tj);
            double sj  = tj * cj;
            int r = 3 - p - q;
            double app = A[p][p], aqq = A[q][q];
            A[p][p] = app - tj*apq;
            A[q][q] = aqq + tj*apq;
            A[p][q] = 0.0; A[q][p] = 0.0;
            double arp = A[r][p], arq = A[r][q];
            A[r][p] = cj*arp - sj*arq; A[p][r] = A[r][p];
            A[r][q] = sj*arp + cj*arq; A[q][r] = A[r][q];
            #pragma unroll
            for (int k = 0; k < 3; k++) {
                double vp = V[k][p], vq = V[k][q];
                V[k][p] = cj*vp - sj*vq;
                V[k][q] = sj*vp + cj*vq;
            }
        }
    }
    double wv[3] = { A[0][0], A[1][1], A[2][2] };
    int i0 = 0, i1 = 1, i2 = 2;
    if (wv[i0] < wv[i1]) { int t = i0; i0 = i1; i1 = t; }
    if (wv[i0] < wv[i2]) { int t = i0; i0 = i2; i2 = t; }
    if (wv[i1] < wv[i2]) { int t = i1; i1 = i2; i2 = t; }
    double v0[3] = { V[0][i0], V[1][i0], V[2][i0] };
    double v1[3] = { V[0][i1], V[1][i1], V[2][i1] };
    double v2[3] = { V[0][i2], V[1][i2], V[2][i2] };
    double s0 = sqrt(fmax(wv[i0], 0.0));
    double Rg[3][3];
    if (s0 < 1e-200) {
        Rg[0][0]=1; Rg[0][1]=0; Rg[0][2]=0;
        Rg[1][0]=0; Rg[1][1]=1; Rg[1][2]=0;
        Rg[2][0]=0; Rg[2][1]=0; Rg[2][2]=1;
    } else {
        double u0[3], u1[3], u2[3];
        #pragma unroll
        for (int i = 0; i < 3; i++)
            u0[i] = H[i][0]*v0[0] + H[i][1]*v0[1] + H[i][2]*v0[2];
        double n0 = sqrt(u0[0]*u0[0] + u0[1]*u0[1] + u0[2]*u0[2]);
        if (n0 > 0.0) { u0[0]/=n0; u0[1]/=n0; u0[2]/=n0; }
        else { u0[0]=1; u0[1]=0; u0[2]=0; }
        #pragma unroll
        for (int i = 0; i < 3; i++)
            u1[i] = H[i][0]*v1[0] + H[i][1]*v1[1] + H[i][2]*v1[2];
        double dp = u0[0]*u1[0] + u0[1]*u1[1] + u0[2]*u1[2];
        u1[0] -= dp*u0[0]; u1[1] -= dp*u0[1]; u1[2] -= dp*u0[2];
        double n1 = sqrt(u1[0]*u1[0] + u1[1]*u1[1] + u1[2]*u1[2]);
        if (n1 > 1e-12 * n0) { u1[0]/=n1; u1[1]/=n1; u1[2]/=n1; }
        else {
            double tv[3] = { (fabs(u0[0]) < 0.9) ? 1.0 : 0.0,
                             (fabs(u0[0]) < 0.9) ? 0.0 : 1.0, 0.0 };
            cross3d(u0, tv, u1);
            double nn = sqrt(u1[0]*u1[0] + u1[1]*u1[1] + u1[2]*u1[2]);
            u1[0]/=nn; u1[1]/=nn; u1[2]/=nn;
        }
        cross3d(u0, u1, u2);                    // det(U) = +1
        double c12[3]; cross3d(v1, v2, c12);
        double detV = v0[0]*c12[0] + v0[1]*c12[1] + v0[2]*c12[2];
        double dsg = (detV >= 0.0) ? 1.0 : -1.0;
        #pragma unroll
        for (int r = 0; r < 3; r++)
            #pragma unroll
            for (int c = 0; c < 3; c++)
                Rg[r][c] = v0[r]*u0[c] + v1[r]*u1[c] + dsg*v2[r]*u2[c];
    }
    double cP[3] = { sP[0]*inv_n, sP[1]*inv_n, sP[2]*inv_n };
    double cQ[3] = { sQ[0]*inv_n, sQ[1]*inv_n, sQ[2]*inv_n };
    #pragma unroll
    for (int i = 0; i < 3; i++) {
        rt[3*i+0] = (float)Rg[i][0];
        rt[3*i+1] = (float)Rg[i][1];
        rt[3*i+2] = (float)Rg[i][2];
        rt[9+i] = (float)(cQ[i] - (Rg[i][0]*cP[0] + Rg[i][1]*cP[1] + Rg[i][2]*cP[2]));
    }
}

// ---------------------------------------------------------------------------
// rsvd_k: THREAD per domain. Reduce own contiguous 1200 B of pos (float4,
// M hoisted per 20/40-node segment) into 15 register sums, then run the SVD.
// All 64 lanes useful in both phases; no sums round-trip through HBM.
// ---------------------------------------------------------------------------
__device__ inline void acc15(float a[15], float p0, float p1, float p2,
                             float q0, float q1, float q2)
{
    a[0]+=p0;    a[1]+=p1;    a[2]+=p2;
    a[3]+=q0;    a[4]+=q1;    a[5]+=q2;
    a[6]+=p0*q0; a[7]+=p0*q1; a[8]+=p0*q2;
    a[9]+=p1*q0; a[10]+=p1*q1;a[11]+=p1*q2;
    a[12]+=p2*q0;a[13]+=p2*q1;a[14]+=p2*q2;
}

__global__ __launch_bounds__(256) void rsvd_k(const float* __restrict__ pos,
                                              const float* __restrict__ out,
                                              float* __restrict__ rt)
{
    int d = blockIdx.x * 256 + threadIdx.x;
    if (d >= N_DOMAIN) return;
    const float4* pv4 = (const float4*)pos;
    const float* Mf = out + M1_OFF;
    float a[15];
    #pragma unroll
    for (int k = 0; k < 15; k++) a[k] = 0.f;

    if (d >= N_TWIST / N_PER_DOM) {
        // high domain: P == Q, no M. 100 nodes = 75 float4s.
        int base = 75 * d;
        for (int c = 0; c < 25; c++) {
            float4 f0 = pv4[base + 3*c + 0];
            float4 f1 = pv4[base + 3*c + 1];
            float4 f2 = pv4[base + 3*c + 2];
            acc15(a, f0.x, f0.y, f0.z, f0.x, f0.y, f0.z);
            acc15(a, f0.w, f1.x, f1.y, f0.w, f1.x, f1.y);
            acc15(a, f1.z, f1.w, f2.x, f1.z, f1.w, f2.x);
            acc15(a, f2.y, f2.z, f2.w, f2.y, f2.z, f2.w);
        }
    } else {
        // low domain: P = M[group(n)] * Q. Segment by group (len 20 or 40).
        int n = d * N_PER_DOM, end = n + N_PER_DOM;
        while (n < end) {
            int g = n / K_TWIST;
            int segEnd = min(end, K_TWIST * (g + 1));
            const float* m = Mf + 12 * g;
            float m0=m[0],m1=m[1],m2=m[2],m3=m[3],m4=m[4],m5=m[5];
            float m6=m[6],m7=m[7],m8=m[8],m9=m[9],m10=m[10],m11=m[11];
            int chunks = (segEnd - n) >> 2;         // 5 or 10
            int base = (3 * n) >> 2;                // float4 index (aligned)
            for (int c = 0; c < chunks; c++) {
                float4 f0 = pv4[base + 3*c + 0];
                float4 f1 = pv4[base + 3*c + 1];
                float4 f2 = pv4[base + 3*c + 2];
                float q0, q1, q2, p0, p1, p2;
                q0=f0.x; q1=f0.y; q2=f0.z;
                p0=m0*q0+m1*q1+m2*q2+m9; p1=m3*q0+m4*q1+m5*q2+m10; p2=m6*q0+m7*q1+m8*q2+m11;
                acc15(a, p0, p1, p2, q0, q1, q2);
                q0=f0.w; q1=f1.x; q2=f1.y;
                p0=m0*q0+m1*q1+m2*q2+m9; p1=m3*q0+m4*q1+m5*q2+m10; p2=m6*q0+m7*q1+m8*q2+m11;
                acc15(a, p0, p1, p2, q0, q1, q2);
                q0=f1.z; q1=f1.w; q2=f2.x;
                p0=m0*q0+m1*q1+m2*q2+m9; p1=m3*q0+m4*q1+m5*q2+m10; p2=m6*q0+m7*q1+m8*q2+m11;
                acc15(a, p0, p1, p2, q0, q1, q2);
                q0=f2.y; q1=f2.z; q2=f2.w;
                p0=m0*q0+m1*q1+m2*q2+m9; p1=m3*q0+m4*q1+m5*q2+m10; p2=m6*q0+m7*q1+m8*q2+m11;
                acc15(a, p0, p1, p2, q0, q1, q2);
            }
            n = segEnd;
        }
    }
    kabsch_from_sums(a, rt + (size_t)d * 12);
}

// ---------------------------------------------------------------------------
// apply_low_k: out[n] = W[d] * (Mf[g] * pos[n]) + t[d], n < N_TWIST.
// Reads Mf (out-high scratch) — must precede apply_high_k.
// ---------------------------------------------------------------------------
__global__ void apply_low_k(const float* __restrict__ pos,
                            const float* __restrict__ rt,
                            float* __restrict__ out)
{
    int n = blockIdx.x * 256 + threadIdx.x;
    if (n >= N_TWIST) return;
    const float* m = out + M1_OFF + 12 * (n / K_TWIST);
    const float* w = rt + 12 * (n / N_PER_DOM);
    float q0 = pos[3*n+0], q1 = pos[3*n+1], q2 = pos[3*n+2];
    float p0 = m[0]*q0 + m[1]*q1 + m[2]*q2 + m[9];
    float p1 = m[3]*q0 + m[4]*q1 + m[5]*q2 + m[10];
    float p2 = m[6]*q0 + m[7]*q1 + m[8]*q2 + m[11];
    out[3*n+0] = w[0]*p0 + w[1]*p1 + w[2]*p2 + w[9];
    out[3*n+1] = w[3]*p0 + w[4]*p1 + w[5]*p2 + w[10];
    out[3*n+2] = w[6]*p0 + w[7]*p1 + w[8]*p2 + w[11];
}

// ---------------------------------------------------------------------------
// apply_high_k: out[n] = W[d] * pos[n] + t[d], n >= N_TWIST. Overwrites the
// out-high scratch (M0/M1/bp) — all consumed by now. rt lives in ws.
// ---------------------------------------------------------------------------
__global__ void apply_high_k(const float* __restrict__ pos,
                             const float* __restrict__ rt,
                             float* __restrict__ out)
{
    int i = blockIdx.x * 256 + threadIdx.x;
    int n = N_TWIST + i;
    if (n >= N_NODE) return;
    const float* w = rt + 12 * (n / N_PER_DOM);
    float q0 = pos[3*n+0], q1 = pos[3*n+1], q2 = pos[3*n+2];
    out[3*n+0] = w[0]*q0 + w[1]*q1 + w[2]*q2 + w[9];
    out[3*n+1] = w[3]*q0 + w[4]*q1 + w[5]*q2 + w[10];
    out[3*n+2] = w[6]*q0 + w[7]*q1 + w[8]*q2 + w[11];
}

// ---------------------------------------------------------------------------
extern "C" void kernel_launch(void* const* d_in, const int* in_sizes, int n_in,
                              void* d_out, int out_size, void* d_ws, size_t ws_size,
                              hipStream_t stream)
{
    const float* pos        = (const float*)d_in[0];
    const float* info_level = (const float*)d_in[1];
    const int*   anno       = (const int*)  d_in[2];
    const float* eps        = (const float*)d_in[6];
    const float* uni        = (const float*)d_in[7];
    const int*   from_prior = (const int*)  d_in[8];
    float* out = (float*)d_out;
    float* rt  = (float*)d_ws;                       // 480,000 B (proven safe)

    // 1. coalesced bond table (random pos gathers + trig, done once)
    gather_k<<<(N_BOND + 255)/256, 256, 0, stream>>>(
        pos, info_level, anno, eps, uni, from_prior, out);

    // 2. all 8 torsion levels in one single-workgroup dispatch
    compose_all_k<<<1, 1024, 0, stream>>>(out);

    // 3. per-domain reduce + SVD (thread per domain)
    rsvd_k<<<(N_DOMAIN + 255)/256, 256, 0, stream>>>(pos, out, rt);

    // 4. low nodes (reads Mf), then 5. high nodes (overwrites scratch)
    apply_low_k<<<(N_TWIST + 255)/256, 256, 0, stream>>>(pos, rt, out);
    apply_high_k<<<(N_NODE - N_TWIST + 255)/256, 256, 0, stream>>>(pos, rt, out);
}

// Round 7
// 186.327 us; speedup vs baseline: 7.9466x; 7.9466x over previous
//
#include <hip/hip_runtime.h>
#include <math.h>

#define N_NODE    1000000
#define N_BOND    100000
#define K_TWIST   40
#define MAX_ORDER 8
#define N_DOMAIN  10000
#define N_PER_DOM 100           // N_NODE / N_DOMAIN
#define N_GROUP   12500         // N_BOND / MAX_ORDER
#define N_TWIST   500000        // N_GROUP * K_TWIST  (nodes >= N_TWIST never twisted)
#define SIGMA_MAXF 3.14159265358979323846f

// Scratch discipline (proven R3..R6):
//   ws: rt table only, 10000*12 floats = 480,000 B (<= 600,000 proven-safe).
//   out-high floats [1.5M, 3.0M):
//     M0 = [1,500,000 , 1,650,000)   150k floats (ping)
//     M1 = [1,650,000 , 1,800,000)   150k floats (pong; final Mf)
//     bp = [1,800,000 , 3,000,000)   100k bonds x 12 floats (gather table)
//   All consumed before apply_high_k overwrites [1.5M, 3M).
// Cost model: ~80 us fixed harness overhead/replay + ~2 us per dispatch.
// R6 lesson: NEVER run the compose chain on one workgroup (1 CU = no MLP,
// 1378 us). Whole-GPU dispatches at ~3 us/level are the cheap barrier.

#define M0_OFF  1500000
#define M1_OFF  1650000
#define BP_OFF  1800000

// ---------------------------------------------------------------------------
// gather_k (R6-verified): one thread per bond, coalesced bond record:
//   bp[12b +0..2]=pos[u], +3..5=pos[v], +6=cos(ang), +7=sin(ang),
//   +8=group(u) or -1, +9=group(v) or -1, +10=valid, +11=pad.
// Random pos gathers + trig happen ONCE here, not per level.
// ---------------------------------------------------------------------------
__global__ __launch_bounds__(256) void gather_k(
    const float* __restrict__ pos, const float* __restrict__ info_level,
    const int* __restrict__ anno, const float* __restrict__ eps,
    const float* __restrict__ uni, const int* __restrict__ from_prior_p,
    float* __restrict__ out)
{
    int b = blockIdx.x * 256 + threadIdx.x;
    if (b >= N_BOND) return;
    int o = b & (MAX_ORDER - 1);
    int u = anno[3*b + 1];
    int v = anno[3*b + 2];
    float info = info_level[b];
    float ang  = eps[b] * (1.0f - info) * SIGMA_MAXF;
    if (from_prior_p[0] != 0 && info == 0.0f) ang = uni[b];
    float4 r0, r1, r2;
    r0.x = pos[3*u+0]; r0.y = pos[3*u+1]; r0.z = pos[3*u+2];
    r0.w = pos[3*v+0]; r1.x = pos[3*v+1]; r1.y = pos[3*v+2];
    r1.z = cosf(ang);  r1.w = sinf(ang);
    r2.x = (u < N_TWIST) ? (float)(u / K_TWIST) : -1.0f;
    r2.y = (v < N_TWIST) ? (float)(v / K_TWIST) : -1.0f;
    r2.z = (anno[3*b] == o) ? 1.0f : 0.0f;
    r2.w = 0.0f;
    float4* bp4 = (float4*)(out + BP_OFF);
    bp4[3*b + 0] = r0;
    bp4[3*b + 1] = r1;
    bp4[3*b + 2] = r2;
}

// ---------------------------------------------------------------------------
// compose_k: ONE LEVEL per whole-GPU dispatch (49 blocks x 256 = 196 waves,
// enough MLP to hide the random M gathers — the R6 single-CU version was
// 170 us/level; this shape was ~3-4 us/level in R5). Reads bp (coalesced)
// + Mp (random), writes Mc. Affine-composition math verified R4/R5/R6.
// ---------------------------------------------------------------------------
__global__ __launch_bounds__(256) void compose_k(float* __restrict__ out, int o)
{
    int g = blockIdx.x * 256 + threadIdx.x;
    if (g >= N_GROUP) return;
    const float4* bp4 = (const float4*)(out + BP_OFF);
    const float* Mp = out + ((o & 1) ? M0_OFF : M1_OFF);  // prev (o>0 only)
    float*       Mc = out + ((o & 1) ? M1_OFF : M0_OFF);  // cur  (o=7 -> M1)
    int b = g * MAX_ORDER + o;
    float4 r0 = bp4[3*b + 0];
    float4 r1 = bp4[3*b + 1];
    float4 r2 = bp4[3*b + 2];
    float* mg = Mc + 12 * g;
    if (r2.z == 0.0f) {                  // invalid bond: identity / carry prev
        if (o == 0) {
            mg[0]=1.f; mg[1]=0.f; mg[2]=0.f;
            mg[3]=0.f; mg[4]=1.f; mg[5]=0.f;
            mg[6]=0.f; mg[7]=0.f; mg[8]=1.f;
            mg[9]=0.f; mg[10]=0.f; mg[11]=0.f;
        } else {
            const float* mp = Mp + 12 * g;
            #pragma unroll
            for (int k = 0; k < 12; k++) mg[k] = mp[k];
        }
        return;
    }
    float pu0 = r0.x, pu1 = r0.y, pu2 = r0.z;
    float pv0 = r0.w, pv1 = r1.x, pv2 = r1.y;
    float c = r1.z, s = r1.w;
    if (o > 0) {
        int gu = (int)r2.x;
        int gv = (int)r2.y;
        if (gu >= 0) {
            const float* m = Mp + 12 * gu;
            float a0 = m[0]*pu0 + m[1]*pu1 + m[2]*pu2 + m[9];
            float a1 = m[3]*pu0 + m[4]*pu1 + m[5]*pu2 + m[10];
            float a2 = m[6]*pu0 + m[7]*pu1 + m[8]*pu2 + m[11];
            pu0 = a0; pu1 = a1; pu2 = a2;
        }
        if (gv >= 0) {
            const float* m = Mp + 12 * gv;
            float a0 = m[0]*pv0 + m[1]*pv1 + m[2]*pv2 + m[9];
            float a1 = m[3]*pv0 + m[4]*pv1 + m[5]*pv2 + m[10];
            float a2 = m[6]*pv0 + m[7]*pv1 + m[8]*pv2 + m[11];
            pv0 = a0; pv1 = a1; pv2 = a2;
        }
    }
    float ax = pv0-pu0, ay = pv1-pu1, az = pv2-pu2;
    float inv = 1.0f / (sqrtf(ax*ax + ay*ay + az*az) + 1e-12f);
    ax *= inv; ay *= inv; az *= inv;
    float t = 1.0f - c;
    float R00 = c + t*ax*ax,     R01 = -s*az + t*ax*ay, R02 =  s*ay + t*ax*az;
    float R10 =  s*az + t*ay*ax, R11 = c + t*ay*ay,     R12 = -s*ax + t*ay*az;
    float R20 = -s*ay + t*az*ax, R21 =  s*ax + t*az*ay, R22 = c + t*az*az;
    if (o == 0) {
        mg[0]=R00; mg[1]=R01; mg[2]=R02;
        mg[3]=R10; mg[4]=R11; mg[5]=R12;
        mg[6]=R20; mg[7]=R21; mg[8]=R22;
        mg[9]  = pv0 - (R00*pv0 + R01*pv1 + R02*pv2);
        mg[10] = pv1 - (R10*pv0 + R11*pv1 + R12*pv2);
        mg[11] = pv2 - (R20*pv0 + R21*pv1 + R22*pv2);
    } else {
        const float* mp = Mp + 12 * g;
        mg[0] = R00*mp[0] + R01*mp[3] + R02*mp[6];
        mg[1] = R00*mp[1] + R01*mp[4] + R02*mp[7];
        mg[2] = R00*mp[2] + R01*mp[5] + R02*mp[8];
        mg[3] = R10*mp[0] + R11*mp[3] + R12*mp[6];
        mg[4] = R10*mp[1] + R11*mp[4] + R12*mp[7];
        mg[5] = R10*mp[2] + R11*mp[5] + R12*mp[8];
        mg[6] = R20*mp[0] + R21*mp[3] + R22*mp[6];
        mg[7] = R20*mp[1] + R21*mp[4] + R22*mp[7];
        mg[8] = R20*mp[2] + R21*mp[5] + R22*mp[8];
        float d0 = mp[9]-pv0, d1 = mp[10]-pv1, d2 = mp[11]-pv2;
        mg[9]  = R00*d0 + R01*d1 + R02*d2 + pv0;
        mg[10] = R10*d0 + R11*d1 + R12*d2 + pv1;
        mg[11] = R20*d0 + R21*d1 + R22*d2 + pv2;
    }
}

// ---------------------------------------------------------------------------
// Kabsch 3x3 SVD from 15 sums (double Jacobi on H^T H) — numerics identical
// to the R1/R3/R4/R5/R6-verified version.
// ---------------------------------------------------------------------------
__device__ inline void cross3d(const double a[3], const double b[3], double r[3])
{
    r[0] = a[1]*b[2] - a[2]*b[1];
    r[1] = a[2]*b[0] - a[0]*b[2];
    r[2] = a[0]*b[1] - a[1]*b[0];
}

__device__ void kabsch_from_sums(const float* s, float* __restrict__ rt)
{
    const double inv_n = 1.0 / (double)N_PER_DOM;
    double sP[3] = { s[0], s[1], s[2] };
    double sQ[3] = { s[3], s[4], s[5] };
    double H[3][3];
    #pragma unroll
    for (int i = 0; i < 3; i++)
        #pragma unroll
        for (int j = 0; j < 3; j++)
            H[i][j] = (double)s[6 + 3*i + j] - sP[i]*sQ[j]*inv_n;
    double A[3][3];
    #pragma unroll
    for (int i = 0; i < 3; i++)
        #pragma unroll
        for (int j = 0; j < 3; j++)
            A[i][j] = H[0][i]*H[0][j] + H[1][i]*H[1][j] + H[2][i]*H[2][j];
    double V[3][3] = {{1,0,0},{0,1,0},{0,0,1}};
    for (int sweep = 0; sweep < 30; sweep++) {
        double off = A[0][1]*A[0][1] + A[0][2]*A[0][2] + A[1][2]*A[1][2];
        double n2  = A[0][0]*A[0][0] + A[1][1]*A[1][1] + A[2][2]*A[2][2];
        if (off <= 1e-28 * n2) break;
        for (int pp = 0; pp < 3; pp++) {
            int p = (pp == 2) ? 1 : 0;
            int q = (pp == 0) ? 1 : 2;
            double apq = A[p][q];
            if (apq == 0.0) continue;
            double tau = (A[q][q] - A[p][p]) / (2.0 * apq);
            double tj  = (tau >= 0.0 ? 1.0 : -1.0) / (fabs(tau) + sqrt(1.0 + tau*tau));
            double cj  = 1.0 / sqrt(1.0 + tj*tj);
            double sj  = tj * cj;
            int r = 3 - p - q;
            double app = A[p][p], aqq = A[q][q];
            A[p][p] = app - tj*apq;
            A[q][q] = aqq + tj*apq;
            A[p][q] = 0.0; A[q][p] = 0.0;
            double arp = A[r][p], arq = A[r][q];
            A[r][p] = cj*arp - sj*arq; A[p][r] = A[r][p];
            A[r][q] = sj*arp + cj*arq; A[q][r] = A[r][q];
            #pragma unroll
            for (int k = 0; k < 3; k++) {
                double vp = V[k][p], vq = V[k][q];
                V[k][p] = cj*vp - sj*vq;
                V[k][q] = sj*vp + cj*vq;
            }
        }
    }
    double wv[3] = { A[0][0], A[1][1], A[2][2] };
    int i0 = 0, i1 = 1, i2 = 2;
    if (wv[i0] < wv[i1]) { int t = i0; i0 = i1; i1 = t; }
    if (wv[i0] < wv[i2]) { int t = i0; i0 = i2; i2 = t; }
    if (wv[i1] < wv[i2]) { int t = i1; i1 = i2; i2 = t; }
    double v0[3] = { V[0][i0], V[1][i0], V[2][i0] };
    double v1[3] = { V[0][i1], V[1][i1], V[2][i1] };
    double v2[3] = { V[0][i2], V[1][i2], V[2][i2] };
    double s0 = sqrt(fmax(wv[i0], 0.0));
    double Rg[3][3];
    if (s0 < 1e-200) {
        Rg[0][0]=1; Rg[0][1]=0; Rg[0][2]=0;
        Rg[1][0]=0; Rg[1][1]=1; Rg[1][2]=0;
        Rg[2][0]=0; Rg[2][1]=0; Rg[2][2]=1;
    } else {
        double u0[3], u1[3], u2[3];
        #pragma unroll
        for (int i = 0; i < 3; i++)
            u0[i] = H[i][0]*v0[0] + H[i][1]*v0[1] + H[i][2]*v0[2];
        double n0 = sqrt(u0[0]*u0[0] + u0[1]*u0[1] + u0[2]*u0[2]);
        if (n0 > 0.0) { u0[0]/=n0; u0[1]/=n0; u0[2]/=n0; }
        else { u0[0]=1; u0[1]=0; u0[2]=0; }
        #pragma unroll
        for (int i = 0; i < 3; i++)
            u1[i] = H[i][0]*v1[0] + H[i][1]*v1[1] + H[i][2]*v1[2];
        double dp = u0[0]*u1[0] + u0[1]*u1[1] + u0[2]*u1[2];
        u1[0] -= dp*u0[0]; u1[1] -= dp*u0[1]; u1[2] -= dp*u0[2];
        double n1 = sqrt(u1[0]*u1[0] + u1[1]*u1[1] + u1[2]*u1[2]);
        if (n1 > 1e-12 * n0) { u1[0]/=n1; u1[1]/=n1; u1[2]/=n1; }
        else {
            double tv[3] = { (fabs(u0[0]) < 0.9) ? 1.0 : 0.0,
                             (fabs(u0[0]) < 0.9) ? 0.0 : 1.0, 0.0 };
            cross3d(u0, tv, u1);
            double nn = sqrt(u1[0]*u1[0] + u1[1]*u1[1] + u1[2]*u1[2]);
            u1[0]/=nn; u1[1]/=nn; u1[2]/=nn;
        }
        cross3d(u0, u1, u2);                    // det(U) = +1
        double c12[3]; cross3d(v1, v2, c12);
        double detV = v0[0]*c12[0] + v0[1]*c12[1] + v0[2]*c12[2];
        double dsg = (detV >= 0.0) ? 1.0 : -1.0;
        #pragma unroll
        for (int r = 0; r < 3; r++)
            #pragma unroll
            for (int c = 0; c < 3; c++)
                Rg[r][c] = v0[r]*u0[c] + v1[r]*u1[c] + dsg*v2[r]*u2[c];
    }
    double cP[3] = { sP[0]*inv_n, sP[1]*inv_n, sP[2]*inv_n };
    double cQ[3] = { sQ[0]*inv_n, sQ[1]*inv_n, sQ[2]*inv_n };
    #pragma unroll
    for (int i = 0; i < 3; i++) {
        rt[3*i+0] = (float)Rg[i][0];
        rt[3*i+1] = (float)Rg[i][1];
        rt[3*i+2] = (float)Rg[i][2];
        rt[9+i] = (float)(cQ[i] - (Rg[i][0]*cP[0] + Rg[i][1]*cP[1] + Rg[i][2]*cP[2]));
    }
}

// ---------------------------------------------------------------------------
// rsvd_k (R6-verified): THREAD per domain. Contiguous float4 reduce of own
// 1200 B of pos (M hoisted per 20/40-node segment) into 15 register sums,
// then the SVD. All 64 lanes useful; no sums round-trip through HBM.
// ---------------------------------------------------------------------------
__device__ inline void acc15(float a[15], float p0, float p1, float p2,
                             float q0, float q1, float q2)
{
    a[0]+=p0;    a[1]+=p1;    a[2]+=p2;
    a[3]+=q0;    a[4]+=q1;    a[5]+=q2;
    a[6]+=p0*q0; a[7]+=p0*q1; a[8]+=p0*q2;
    a[9]+=p1*q0; a[10]+=p1*q1;a[11]+=p1*q2;
    a[12]+=p2*q0;a[13]+=p2*q1;a[14]+=p2*q2;
}

__global__ __launch_bounds__(256) void rsvd_k(const float* __restrict__ pos,
                                              const float* __restrict__ out,
                                              float* __restrict__ rt)
{
    int d = blockIdx.x * 256 + threadIdx.x;
    if (d >= N_DOMAIN) return;
    const float4* pv4 = (const float4*)pos;
    const float* Mf = out + M1_OFF;
    float a[15];
    #pragma unroll
    for (int k = 0; k < 15; k++) a[k] = 0.f;

    if (d >= N_TWIST / N_PER_DOM) {
        int base = 75 * d;
        for (int c = 0; c < 25; c++) {
            float4 f0 = pv4[base + 3*c + 0];
            float4 f1 = pv4[base + 3*c + 1];
            float4 f2 = pv4[base + 3*c + 2];
            acc15(a, f0.x, f0.y, f0.z, f0.x, f0.y, f0.z);
            acc15(a, f0.w, f1.x, f1.y, f0.w, f1.x, f1.y);
            acc15(a, f1.z, f1.w, f2.x, f1.z, f1.w, f2.x);
            acc15(a, f2.y, f2.z, f2.w, f2.y, f2.z, f2.w);
        }
    } else {
        int n = d * N_PER_DOM, end = n + N_PER_DOM;
        while (n < end) {
            int g = n / K_TWIST;
            int segEnd = min(end, K_TWIST * (g + 1));
            const float* m = Mf + 12 * g;
            float m0=m[0],m1=m[1],m2=m[2],m3=m[3],m4=m[4],m5=m[5];
            float m6=m[6],m7=m[7],m8=m[8],m9=m[9],m10=m[10],m11=m[11];
            int chunks = (segEnd - n) >> 2;
            int base = (3 * n) >> 2;
            for (int c = 0; c < chunks; c++) {
                float4 f0 = pv4[base + 3*c + 0];
                float4 f1 = pv4[base + 3*c + 1];
                float4 f2 = pv4[base + 3*c + 2];
                float q0, q1, q2, p0, p1, p2;
                q0=f0.x; q1=f0.y; q2=f0.z;
                p0=m0*q0+m1*q1+m2*q2+m9; p1=m3*q0+m4*q1+m5*q2+m10; p2=m6*q0+m7*q1+m8*q2+m11;
                acc15(a, p0, p1, p2, q0, q1, q2);
                q0=f0.w; q1=f1.x; q2=f1.y;
                p0=m0*q0+m1*q1+m2*q2+m9; p1=m3*q0+m4*q1+m5*q2+m10; p2=m6*q0+m7*q1+m8*q2+m11;
                acc15(a, p0, p1, p2, q0, q1, q2);
                q0=f1.z; q1=f1.w; q2=f2.x;
                p0=m0*q0+m1*q1+m2*q2+m9; p1=m3*q0+m4*q1+m5*q2+m10; p2=m6*q0+m7*q1+m8*q2+m11;
                acc15(a, p0, p1, p2, q0, q1, q2);
                q0=f2.y; q1=f2.z; q2=f2.w;
                p0=m0*q0+m1*q1+m2*q2+m9; p1=m3*q0+m4*q1+m5*q2+m10; p2=m6*q0+m7*q1+m8*q2+m11;
                acc15(a, p0, p1, p2, q0, q1, q2);
            }
            n = segEnd;
        }
    }
    kabsch_from_sums(a, rt + (size_t)d * 12);
}

// ---------------------------------------------------------------------------
// apply_low_k: out[n] = W[d] * (Mf[g] * pos[n]) + t[d], n < N_TWIST.
// Reads Mf (out-high scratch) — must precede apply_high_k.
// ---------------------------------------------------------------------------
__global__ void apply_low_k(const float* __restrict__ pos,
                            const float* __restrict__ rt,
                            float* __restrict__ out)
{
    int n = blockIdx.x * 256 + threadIdx.x;
    if (n >= N_TWIST) return;
    const float* m = out + M1_OFF + 12 * (n / K_TWIST);
    const float* w = rt + 12 * (n / N_PER_DOM);
    float q0 = pos[3*n+0], q1 = pos[3*n+1], q2 = pos[3*n+2];
    float p0 = m[0]*q0 + m[1]*q1 + m[2]*q2 + m[9];
    float p1 = m[3]*q0 + m[4]*q1 + m[5]*q2 + m[10];
    float p2 = m[6]*q0 + m[7]*q1 + m[8]*q2 + m[11];
    out[3*n+0] = w[0]*p0 + w[1]*p1 + w[2]*p2 + w[9];
    out[3*n+1] = w[3]*p0 + w[4]*p1 + w[5]*p2 + w[10];
    out[3*n+2] = w[6]*p0 + w[7]*p1 + w[8]*p2 + w[11];
}

// ---------------------------------------------------------------------------
// apply_high_k: out[n] = W[d] * pos[n] + t[d], n >= N_TWIST. Overwrites the
// out-high scratch (M0/M1/bp) — all consumed by now. rt lives in ws.
// ---------------------------------------------------------------------------
__global__ void apply_high_k(const float* __restrict__ pos,
                             const float* __restrict__ rt,
                             float* __restrict__ out)
{
    int i = blockIdx.x * 256 + threadIdx.x;
    int n = N_TWIST + i;
    if (n >= N_NODE) return;
    const float* w = rt + 12 * (n / N_PER_DOM);
    float q0 = pos[3*n+0], q1 = pos[3*n+1], q2 = pos[3*n+2];
    out[3*n+0] = w[0]*q0 + w[1]*q1 + w[2]*q2 + w[9];
    out[3*n+1] = w[3]*q0 + w[4]*q1 + w[5]*q2 + w[10];
    out[3*n+2] = w[6]*q0 + w[7]*q1 + w[8]*q2 + w[11];
}

// ---------------------------------------------------------------------------
extern "C" void kernel_launch(void* const* d_in, const int* in_sizes, int n_in,
                              void* d_out, int out_size, void* d_ws, size_t ws_size,
                              hipStream_t stream)
{
    const float* pos        = (const float*)d_in[0];
    const float* info_level = (const float*)d_in[1];
    const int*   anno       = (const int*)  d_in[2];
    const float* eps        = (const float*)d_in[6];
    const float* uni        = (const float*)d_in[7];
    const int*   from_prior = (const int*)  d_in[8];
    float* out = (float*)d_out;
    float* rt  = (float*)d_ws;                       // 480,000 B (proven safe)

    // 1. coalesced bond table (random pos gathers + trig, done once)
    gather_k<<<(N_BOND + 255)/256, 256, 0, stream>>>(
        pos, info_level, anno, eps, uni, from_prior, out);

    // 2-9. eight whole-GPU compose levels (ping-pong M0/M1; o=7 -> M1)
    for (int o = 0; o < MAX_ORDER; o++)
        compose_k<<<(N_GROUP + 255)/256, 256, 0, stream>>>(out, o);

    // 10. per-domain reduce + SVD (thread per domain)
    rsvd_k<<<(N_DOMAIN + 255)/256, 256, 0, stream>>>(pos, out, rt);

    // 11. low nodes (reads Mf), then 12. high nodes (overwrites scratch)
    apply_low_k<<<(N_TWIST + 255)/256, 256, 0, stream>>>(pos, rt, out);
    apply_high_k<<<(N_NODE - N_TWIST + 255)/256, 256, 0, stream>>>(pos, rt, out);
}